// Round 7
// baseline (600.144 us; speedup 1.0000x reference)
//
#include <hip/hip_runtime.h>

// SoftCLDiceLoss fully fused, round 7: wave-autonomous register-resident
// morphology with an IN-PLACE single register plane. P[40] (f16x2 per
// lane-row) eroded in place via 2-deep horizontal-min history; E[16]
// snapshots e_k tile rows for the delta; dilate is read-only on P with a
// 2-deep horizontal-max history. Live set ~90 u32; amdgpu_waves_per_eu(4,4)
// pins allocation at 128 VGPRs so the compiler cannot offload the plane to
// AGPRs (round-6 failure: 60 arch VGPRs + AGPR shuffling inflated VALU 2.5x).
// NO LDS, NO barriers. Erosion edge-correctness: stale rows P[0]/P[39] and
// replicated loads are >= true erosion (min-safe); wave-edge DPP zero-fill
// garbage propagates 1 col/step and stays inside the 12-col discard margin.
// Dilation gets exact replicate patches on image-edge bands only.

#define IMG 1024
#define NBC 16
#define LEPS 1e-6f

typedef unsigned int u32;

__device__ __forceinline__ u32 pk_min(u32 a, u32 b) {
    u32 d; asm("v_pk_min_f16 %0, %1, %2" : "=v"(d) : "v"(a), "v"(b)); return d;
}
__device__ __forceinline__ u32 pk_max(u32 a, u32 b) {
    u32 d; asm("v_pk_max_f16 %0, %1, %2" : "=v"(d) : "v"(a), "v"(b)); return d;
}
__device__ __forceinline__ u32 pk_max0(u32 a) {
    u32 d; asm("v_pk_max_f16 %0, %1, 0" : "=v"(d) : "v"(a)); return d;
}
__device__ __forceinline__ u32 pk_add(u32 a, u32 b) {
    u32 d; asm("v_pk_add_f16 %0, %1, %2" : "=v"(d) : "v"(a), "v"(b)); return d;
}
__device__ __forceinline__ u32 pk_fma(u32 a, u32 b, u32 c) {
    u32 d; asm("v_pk_fma_f16 %0, %1, %2, %3" : "=v"(d) : "v"(a), "v"(b), "v"(c)); return d;
}
__device__ __forceinline__ u32 dpp_prev(u32 x) {   // lane i <- i-1 (wave_shl1), 0-fill
    return (u32)__builtin_amdgcn_update_dpp(0, (int)x, 0x130, 0xf, 0xf, true);
}
__device__ __forceinline__ u32 dpp_next(u32 x) {   // lane i <- i+1 (wave_shr1), 0-fill
    return (u32)__builtin_amdgcn_update_dpp(0, (int)x, 0x138, 0xf, 0xf, true);
}
__device__ __forceinline__ u32 alignh(u32 hi, u32 lo) {   // (lo.hi16 | hi.lo16<<16)
    return __builtin_amdgcn_alignbit(hi, lo, 16);
}
__device__ __forceinline__ u32 swap16(u32 x) { return alignh(x, x); }
__device__ __forceinline__ float sigmoidf(float x) { return 1.0f / (1.0f + __expf(-x)); }

// horizontal 3-wide min/max of one packed row (6 VALU: 2 dpp, 2 align, 2 min/max)
__device__ __forceinline__ u32 hmin3(u32 x) {
    u32 dm = dpp_prev(x), dp = dpp_next(x);
    return pk_min(pk_min(alignh(x, dm), x), alignh(dp, x));
}
__device__ __forceinline__ u32 hmax3(u32 x) {
    u32 dm = dpp_prev(x), dp = dpp_next(x);
    return pk_max(pk_max(alignh(x, dm), x), alignh(dp, x));
}

__global__ __launch_bounds__(256)
__attribute__((amdgpu_waves_per_eu(4, 4)))
void skel_wave_kernel(const float* __restrict__ pred,
                      const float* __restrict__ target,
                      float* __restrict__ ws)
{
    const int tid    = threadIdx.x;
    const int lane   = tid & 63;
    const int waveId = tid >> 6;

    const int bc  = blockIdx.z & (NBC - 1);
    const int img = blockIdx.z >> 4;
    const int tr0 = (blockIdx.y * 4 + waveId) * 16;   // tile row base (0..1008)
    const int cb0 = blockIdx.x * 104;                 // data col base
    const int wc0 = cb0 - 12;                         // window col 0 -> image col

    const float* src = (img == 0) ? pred : target;
    const size_t base = (size_t)bc * (size_t)(IMG * IMG);

    const bool edgeT = (tr0 == 0);
    const bool edgeB = (tr0 == IMG - 16);
    const bool edgeL = (blockIdx.x == 0);
    const bool edgeR = (blockIdx.x == 9);

    const int ic0 = wc0 + 2 * lane;                   // image col of lo half

    // ---- load 40-row region into plane P (f16x2 per lane-row) ----
    u32 P[40];
#pragma unroll
    for (int i = 0; i < 40; ++i) {
        int ir = min(max(tr0 - 12 + i, 0), IMG - 1);
        const float* rowp = src + base + (size_t)ir * IMG;
        float a, b;
        if (!(edgeL || edgeR)) {
            float2 f2 = *(const float2*)(rowp + ic0);
            a = f2.x; b = f2.y;
        } else {
            a = rowp[min(max(ic0, 0), IMG - 1)];
            b = rowp[min(max(ic0 + 1, 0), IMG - 1)];
        }
        if (img == 0) { a = sigmoidf(a); b = sigmoidf(b); }
        else { a = fminf(fmaxf(a, 0.f), 1.f); b = fminf(fmaxf(b, 0.f), 1.f); }
        _Float16 ha = (_Float16)a, hb = (_Float16)b;
        unsigned short ua, ub;
        __builtin_memcpy(&ua, &ha, 2);
        __builtin_memcpy(&ub, &hb, 2);
        P[i] = (u32)ua | ((u32)ub << 16);
    }

    u32 E[16];                                        // e_k snapshot (tile rows)
    u32 nS[16];                                       // negated skel: nS = -S
#pragma unroll
    for (int j = 0; j < 16; ++j) nS[j] = 0u;

#pragma unroll 1
    for (int k = 0; k < 11; ++k) {
        // ---- erode 3x3 (min) in place on P, rows 1..38 (P[0],P[39] stale-safe).
        //      horizontal-first, 2-deep hh history; snapshot tile rows into E.
        {
            u32 hm1 = hmin3(P[0]);
            u32 h0  = hmin3(P[1]);
#pragma unroll
            for (int r = 1; r <= 38; ++r) {
                u32 hp1 = hmin3(P[r + 1]);
                if (r >= 12 && r <= 27) E[r - 12] = P[r];   // old e_k value
                P[r] = pk_min(pk_min(hm1, h0), hp1);
                hm1 = h0; h0 = hp1;
            }
        }

        // ---- dilate 3x3 (max) read-only on P (= e_{k+1}), rows 12..27;
        //      delta vs E; skel update. 2-deep hmax history.
        {
            u32 gm1 = hmax3(edgeT ? P[12] : P[11]);
            u32 g0  = hmax3(P[12]);
#pragma unroll
            for (int j = 12; j <= 27; ++j) {
                u32 gp1 = hmax3((j == 27) ? (edgeB ? P[27] : P[28]) : P[j + 1]);
                u32 m = pk_max(pk_max(gm1, g0), gp1);
                gm1 = g0; g0 = gp1;

                // image-edge column repair (replicate), block-uniform branches
                if (edgeL) {   // out col12.lo := max over rows of cols {12,13} (lane 6)
                    u32 up = (j == 12 && edgeT) ? P[12] : P[j - 1];
                    u32 dn = (j == 27 && edgeB) ? P[27] : P[j + 1];
                    u32 v  = pk_max(pk_max(up, P[j]), dn);
                    u32 pm = pk_max(v, swap16(v));
                    if (lane == 6) m = (m & 0xFFFF0000u) | (pm & 0xFFFFu);
                }
                if (edgeR) {   // out col1023.hi := max over rows of cols {1022,1023} (lane 49)
                    u32 up = (j == 12 && edgeT) ? P[12] : P[j - 1];
                    u32 dn = (j == 27 && edgeB) ? P[27] : P[j + 1];
                    u32 v  = pk_max(pk_max(up, P[j]), dn);
                    u32 pm = pk_max(v, swap16(v));
                    if (lane == 49) m = (m & 0x0000FFFFu) | (pm & 0xFFFF0000u);
                }

                u32 d = pk_max0(pk_add(E[j - 12], m ^ 0x80008000u));  // relu(e_k - D)
                u32 t = pk_max0(pk_fma(nS[j - 12], d, d));            // relu(d - S*d)
                nS[j - 12] = pk_add(nS[j - 12], t ^ 0x80008000u);     // nS -= t
            }
        }
    }

    // ---- per-lane column validity (window col in [12,115], image col <1024) ----
    const int wlo = 2 * lane, whi = 2 * lane + 1;
    const float mLo = (wlo >= 12 && wlo <= 115 && ic0 <= IMG - 1) ? 1.f : 0.f;
    const float mHi = (whi >= 12 && whi <= 115 && ic0 + 1 <= IMG - 1) ? 1.f : 0.f;

    // ---- sums: sum(skel), sum(skel * other) over tile rows ----
    const float* osrc = (img == 0) ? target : pred;
    float s_sum = 0.f, sp_sum = 0.f;
#pragma unroll
    for (int j = 0; j < 16; ++j) {
        int ir = tr0 + j;
        const float* rowp = osrc + base + (size_t)ir * IMG;
        float oa, ob;
        if (!(edgeL || edgeR)) {
            float2 f2 = *(const float2*)(rowp + ic0);
            oa = f2.x; ob = f2.y;
        } else {
            oa = rowp[min(max(ic0, 0), IMG - 1)];
            ob = rowp[min(max(ic0 + 1, 0), IMG - 1)];
        }
        if (img == 1) { oa = sigmoidf(oa); ob = sigmoidf(ob); }
        unsigned short ul = (unsigned short)(nS[j] & 0xFFFFu);
        unsigned short uh = (unsigned short)(nS[j] >> 16);
        _Float16 hl, hh;
        __builtin_memcpy(&hl, &ul, 2);
        __builtin_memcpy(&hh, &uh, 2);
        float svLo = -(float)hl * mLo;
        float svHi = -(float)hh * mHi;
        s_sum  += svLo + svHi;
        sp_sum += svLo * oa + svHi * ob;
    }

#pragma unroll
    for (int off = 32; off > 0; off >>= 1) {
        s_sum  += __shfl_down(s_sum,  off, 64);
        sp_sum += __shfl_down(sp_sum, off, 64);
    }
    if (lane == 0) {
        float* acc = ws + (size_t)blockIdx.z * 2;
        atomicAdd(acc + 0, sp_sum);   // sum skel * other
        atomicAdd(acc + 1, s_sum);    // sum skel
    }
}

__global__ void finalize_kernel(const float* __restrict__ ws, float* __restrict__ out)
{
    if (threadIdx.x == 0) {
        float acc = 0.0f;
        for (int bc = 0; bc < NBC; ++bc) {
            float spt = ws[(0 * NBC + bc) * 2 + 0];
            float sp  = ws[(0 * NBC + bc) * 2 + 1];
            float stp = ws[(1 * NBC + bc) * 2 + 0];
            float st  = ws[(1 * NBC + bc) * 2 + 1];
            float tprec = spt / (sp + LEPS);
            float tsens = stp / (st + LEPS);
            acc += 1.0f - 2.0f * tprec * tsens / (tprec + tsens + LEPS);
        }
        out[0] = acc / (float)NBC;
    }
}

extern "C" void kernel_launch(void* const* d_in, const int* in_sizes, int n_in,
                              void* d_out, int out_size, void* d_ws, size_t ws_size,
                              hipStream_t stream) {
    const float* pred   = (const float*)d_in[0];
    const float* target = (const float*)d_in[1];
    float* ws  = (float*)d_ws;
    float* out = (float*)d_out;

    hipMemsetAsync(d_ws, 0, 2 * NBC * 2 * sizeof(float), stream);

    dim3 grid(10, 16, 2 * NBC);   // 10 col-bands x (16 blocks x 4 waves = 64 row-bands) x 32 images
    skel_wave_kernel<<<grid, 256, 0, stream>>>(pred, target, ws);
    finalize_kernel<<<1, 64, 0, stream>>>(ws, out);
}